// Round 3
// baseline (2582.548 us; speedup 1.0000x reference)
//
#include <hip/hip_runtime.h>
#include <hip/hip_bf16.h>

#define B_ 4
#define P_ 12
#define Q_ 12
#define N_ 2048
#define D_ 32
#define ELLW 96

typedef __hip_bfloat16 bf16;

// Dual-path input load: flag==0 -> bf16 storage, flag==1 -> fp32 storage.
__device__ __forceinline__ float ld(const void* p, int i, int flag) {
    if (flag) return ((const float*)p)[i];
    unsigned int u = ((const unsigned short*)p)[i];
    return __uint_as_float(u << 16);
}

// ------------------------------------------------------------ dtype detector
// L is ~98% zeros; nonzeros are in [-1, -0.0158]. If the buffer is truly bf16,
// every half-word interprets to a sane value. If it is fp32, the low half-words
// of nonzero entries interpret to denormal-scale garbage -> flag fp32.
__global__ void k_detect(const void* L, int* flagp) {
    __shared__ int c;
    if (threadIdx.x == 0) c = 0;
    __syncthreads();
    const unsigned short* p = (const unsigned short*)L;
    int bad = 0;
    for (int i = threadIdx.x; i < 8192; i += 256) {
        unsigned int u = p[i];
        float v = __uint_as_float(u << 16);
        if (isnan(v) || isinf(v) || (v != 0.f && (fabsf(v) < 1e-8f || fabsf(v) > 1e4f))) bad = 1;
    }
    atomicOr(&c, bad);
    __syncthreads();
    if (threadIdx.x == 0) *flagp = (c != 0) ? 1 : 0;
}

// ---------------------------------------------------------------- ELL build
__global__ __launch_bounds__(256) void k_build_ell(const void* L, const int* flagp,
                                                   float* __restrict__ ell_val,
                                                   int* __restrict__ ell_col,
                                                   int* __restrict__ ell_cnt) {
    int flag = *flagp;
    int row = blockIdx.x;
    __shared__ int cnt;
    if (threadIdx.x == 0) cnt = 0;
    __syncthreads();
    for (int c = threadIdx.x; c < N_; c += 256) {
        float v = ld(L, row * N_ + c, flag);
        if (v != 0.0f) {
            int s = atomicAdd(&cnt, 1);
            if (s < ELLW) { ell_col[row * ELLW + s] = c; ell_val[row * ELLW + s] = v; }
        }
    }
    __syncthreads();
    if (threadIdx.x == 0) ell_cnt[row] = cnt < ELLW ? cnt : ELLW;
}

// ---------------------------------------------------------------- se = relu(SE@W1+b1)@W2+b2
__global__ __launch_bounds__(256) void k_se(const void* SE, const void* W1, const void* B1,
                                            const void* W2, const void* B2, const int* flagp,
                                            float* __restrict__ se) {
    __shared__ float w1[1024], w2[1024], c1[32], c2[32];
    __shared__ float srow[8][33], hid[8][33];
    int flag = *flagp;
    int tid = threadIdx.x;
    for (int i = tid; i < 1024; i += 256) { w1[i] = ld(W1, i, flag); w2[i] = ld(W2, i, flag); }
    if (tid < 32) { c1[tid] = ld(B1, tid, flag); c2[tid] = ld(B2, tid, flag); }
    int r = tid >> 5, d = tid & 31;
    int row = blockIdx.x * 8 + r;
    srow[r][d] = ld(SE, row * 32 + d, flag);
    __syncthreads();
    float a = c1[d];
    #pragma unroll
    for (int i = 0; i < 32; ++i) a += srow[r][i] * w1[i * 32 + d];
    hid[r][d] = fmaxf(a, 0.f);
    __syncthreads();
    float o = c2[d];
    #pragma unroll
    for (int i = 0; i < 32; ++i) o += hid[r][i] * w2[i * 32 + d];
    se[row * 32 + d] = o;
}

// ---------------------------------------------------------------- te (rows b*P+t, t<P)
__global__ __launch_bounds__(256) void k_te(const int* __restrict__ TE, const void* W1, const void* B1,
                                            const void* W2, const void* B2, const int* flagp,
                                            float* __restrict__ te) {
    __shared__ float w2[1024], c1[32], c2[32];
    __shared__ float hid[8][33];
    int flag = *flagp;
    int tid = threadIdx.x;
    for (int i = tid; i < 1024; i += 256) w2[i] = ld(W2, i, flag);
    if (tid < 32) { c1[tid] = ld(B1, tid, flag); c2[tid] = ld(B2, tid, flag); }
    __syncthreads();
    int r = tid >> 5, d = tid & 31;
    int row = blockIdx.x * 8 + r;   // row = b*P + t
    int b = row / P_, t = row % P_;
    int day = TE[(b * (P_ + Q_) + t) * 2 + 0];
    int tod = TE[(b * (P_ + Q_) + t) * 2 + 1];
    float a = ld(W1, day * 32 + d, flag) + ld(W1, (7 + tod) * 32 + d, flag) + c1[d];
    hid[r][d] = fmaxf(a, 0.f);
    __syncthreads();
    float o = c2[d];
    #pragma unroll
    for (int i = 0; i < 32; ++i) o += hid[r][i] * w2[i * 32 + d];
    te[row * 32 + d] = o;
}

// ---------------------------------------------------------------- xt for one step t: [b][n][d]
__global__ __launch_bounds__(256) void k_xt(int t, const void* X, const void* W_in1, const void* b_in1,
                                            const void* W_in2, const void* b_in2,
                                            const float* __restrict__ se, const float* __restrict__ te,
                                            const int* flagp, float* __restrict__ xt) {
    __shared__ float w2[1024], w1[32], c1[32], c2[32];
    __shared__ float hid[8][33];
    int flag = *flagp;
    int tid = threadIdx.x;
    for (int i = tid; i < 1024; i += 256) w2[i] = ld(W_in2, i, flag);
    if (tid < 32) { w1[tid] = ld(W_in1, tid, flag); c1[tid] = ld(b_in1, tid, flag); c2[tid] = ld(b_in2, tid, flag); }
    __syncthreads();
    int r = tid >> 5, d = tid & 31;
    int g = blockIdx.x * 8 + r;              // g = b*N + n
    int b = g / N_, n = g % N_;
    float xv = ld(X, (b * P_ + t) * N_ + n, flag);
    hid[r][d] = fmaxf(xv * w1[d] + c1[d], 0.f);
    __syncthreads();
    float o = c2[d] + se[n * 32 + d] + te[(b * P_ + t) * 32 + d];
    #pragma unroll
    for (int i = 0; i < 32; ++i) o += hid[r][i] * w2[i * 32 + d];
    xt[(size_t)g * 32 + d] = o;
}

// ---------------------------------------------------------------- Chebyshev hop: out = L@in (prev null) or 2*L@in - prev; B slices
__global__ __launch_bounds__(256) void k_spmm(const float* __restrict__ in, const float* __restrict__ prev,
                                              float* __restrict__ out,
                                              const float* __restrict__ ell_val, const int* __restrict__ ell_col,
                                              const int* __restrict__ ell_cnt) {
    int d = threadIdx.x & 31, r = threadIdx.x >> 5;
    int slice = blockIdx.x >> 8;
    int row = (blockIdx.x & 255) * 8 + r;
    const float* inS = in + (size_t)slice * N_ * D_;
    int cnt = ell_cnt[row];
    const int* cols = ell_col + row * ELLW;
    const float* vals = ell_val + row * ELLW;
    float acc = 0.f;
    for (int i = 0; i < cnt; ++i) acc += vals[i] * inS[cols[i] * 32 + d];
    size_t idx = (size_t)slice * N_ * D_ + (size_t)row * 32 + d;
    out[idx] = prev ? (2.f * acc - prev[idx]) : acc;
}

// ---------------------------------------------------------------- gate: two-phase (x half, h half) GEMM + sigmoid; emit u, r*h
__global__ __launch_bounds__(256) void k_gate(const float* __restrict__ xt, const float* __restrict__ XT1,
                                              const float* __restrict__ XT2,
                                              const float* __restrict__ H, const float* __restrict__ HC1,
                                              const float* __restrict__ HC2,
                                              const void* W_gate, const void* b_gate,
                                              const float* __restrict__ ell_val, const int* __restrict__ ell_col,
                                              const int* __restrict__ ell_cnt, const int* flagp,
                                              float* __restrict__ U, float* __restrict__ RH) {
    __shared__ float wg[128 * 64];   // 32 KB, reused across phases
    __shared__ float st[8][128];
    int flag = *flagp;
    int tid = threadIdx.x;
    int r = tid >> 5, d = tid & 31;
    int b = blockIdx.x >> 8;
    int row = (blockIdx.x & 255) * 8 + r;
    size_t base = ((size_t)b * N_ + row) * 32;
    int cnt = ell_cnt[row];
    const int* cols = ell_col + row * ELLW;
    const float* vals = ell_val + row * ELLW;
    float ag1 = ld(b_gate, d, flag), ag2 = ld(b_gate, 32 + d, flag);

    // ---- phase 1: x half (W_gate rows k*64 + j, j<32)
    for (int i = tid; i < 128 * 64; i += 256) {
        int kk = i >> 6, j = i & 63;
        wg[i] = ld(W_gate, ((kk >> 5) * 64 + (kk & 31)) * 64 + j, flag);
    }
    {
        const float* sl2 = XT2 + (size_t)b * N_ * D_;
        float acc = 0.f;
        for (int i = 0; i < cnt; ++i) acc += vals[i] * sl2[cols[i] * 32 + d];
        st[r][d]      = xt[base + d];
        st[r][32 + d] = XT1[base + d];
        st[r][64 + d] = XT2[base + d];
        st[r][96 + d] = 2.f * acc - XT1[base + d];
    }
    __syncthreads();
    #pragma unroll 8
    for (int kk = 0; kk < 128; ++kk) {
        float v = st[r][kk];
        ag1 += v * wg[kk * 64 + d];
        ag2 += v * wg[kk * 64 + 32 + d];
    }
    __syncthreads();   // done reading wg/st before overwrite

    // ---- phase 2: h half (W_gate rows k*64 + 32 + j)
    for (int i = tid; i < 128 * 64; i += 256) {
        int kk = i >> 6, j = i & 63;
        wg[i] = ld(W_gate, ((kk >> 5) * 64 + 32 + (kk & 31)) * 64 + j, flag);
    }
    float hv;
    {
        const float* sl2 = HC2 + (size_t)b * N_ * D_;
        float acc = 0.f;
        for (int i = 0; i < cnt; ++i) acc += vals[i] * sl2[cols[i] * 32 + d];
        hv = H[base + d];
        st[r][d]      = hv;
        st[r][32 + d] = HC1[base + d];
        st[r][64 + d] = HC2[base + d];
        st[r][96 + d] = 2.f * acc - HC1[base + d];
    }
    __syncthreads();
    #pragma unroll 8
    for (int kk = 0; kk < 128; ++kk) {
        float v = st[r][kk];
        ag1 += v * wg[kk * 64 + d];
        ag2 += v * wg[kk * 64 + 32 + d];
    }
    float rv = 1.f / (1.f + expf(-ag1));
    float uv = 1.f / (1.f + expf(-ag2));
    U[base + d] = uv;
    RH[base + d] = rv * hv;
}

// ---------------------------------------------------------------- cand: single-phase 256-row GEMM + tanh + h update
__global__ __launch_bounds__(256) void k_cand(const float* __restrict__ xt, const float* __restrict__ XT1,
                                              const float* __restrict__ XT2,
                                              const float* __restrict__ RHv, const float* __restrict__ RC1,
                                              const float* __restrict__ RC2,
                                              const void* W_cand, const void* b_cand,
                                              const float* __restrict__ ell_val, const int* __restrict__ ell_col,
                                              const int* __restrict__ ell_cnt, const int* flagp,
                                              const float* __restrict__ U, float* __restrict__ H) {
    __shared__ float wc[256 * 32];   // 32 KB, direct copy of W_cand
    __shared__ float st[8][256];     // feature order f = k*64 + j matches weight rows
    int flag = *flagp;
    int tid = threadIdx.x;
    for (int i = tid; i < 256 * 32; i += 256) wc[i] = ld(W_cand, i, flag);
    int r = tid >> 5, d = tid & 31;
    int b = blockIdx.x >> 8;
    int row = (blockIdx.x & 255) * 8 + r;
    size_t base = ((size_t)b * N_ + row) * 32;
    int cnt = ell_cnt[row];
    const int* cols = ell_col + row * ELLW;
    const float* vals = ell_val + row * ELLW;
    {
        const float* x2 = XT2 + (size_t)b * N_ * D_;
        const float* r2 = RC2 + (size_t)b * N_ * D_;
        float accx = 0.f, accr = 0.f;
        for (int i = 0; i < cnt; ++i) {
            accx += vals[i] * x2[cols[i] * 32 + d];
            accr += vals[i] * r2[cols[i] * 32 + d];
        }
        st[r][d]            = xt[base + d];
        st[r][64 + d]       = XT1[base + d];
        st[r][128 + d]      = XT2[base + d];
        st[r][192 + d]      = 2.f * accx - XT1[base + d];
        st[r][32 + d]       = RHv[base + d];
        st[r][96 + d]       = RC1[base + d];
        st[r][160 + d]      = RC2[base + d];
        st[r][224 + d]      = 2.f * accr - RC1[base + d];
    }
    __syncthreads();
    float pre = ld(b_cand, d, flag);
    #pragma unroll 8
    for (int f = 0; f < 256; ++f) pre += st[r][f] * wc[f * 32 + d];
    float c = tanhf(pre);
    float uv = U[base + d];
    H[base + d] = uv * H[base + d] + (1.f - uv) * c;
}

// ---------------------------------------------------------------- output head: y[b,q,n], dual-dtype store
__global__ __launch_bounds__(256) void k_out(const float* __restrict__ H, const void* W1, const void* B1,
                                             const void* W2, const void* B2, const int* flagp,
                                             void* __restrict__ out) {
    __shared__ float w1[1024], w2[384], c1[32], c2[12];
    int flag = *flagp;
    int tid = threadIdx.x;
    for (int i = tid; i < 1024; i += 256) w1[i] = ld(W1, i, flag);
    for (int i = tid; i < 384; i += 256) w2[i] = ld(W2, i, flag);
    if (tid < 32) c1[tid] = ld(B1, tid, flag);
    if (tid < 12) c2[tid] = ld(B2, tid, flag);
    __syncthreads();
    int gid = blockIdx.x * 256 + tid;
    int b = gid / N_, n = gid % N_;
    float hrow[32];
    #pragma unroll
    for (int i = 0; i < 32; ++i) hrow[i] = H[(size_t)(b * N_ + n) * 32 + i];
    float hid[32];
    #pragma unroll
    for (int j = 0; j < 32; ++j) {
        float a = c1[j];
        #pragma unroll
        for (int i = 0; i < 32; ++i) a += hrow[i] * w1[i * 32 + j];
        hid[j] = fmaxf(a, 0.f);
    }
    for (int q = 0; q < 12; ++q) {
        float a = c2[q];
        #pragma unroll
        for (int j = 0; j < 32; ++j) a += hid[j] * w2[j * 12 + q];
        size_t idx = ((size_t)b * Q_ + q) * N_ + n;
        if (flag) ((float*)out)[idx] = a;
        else ((bf16*)out)[idx] = __float2bfloat16(a);
    }
}

extern "C" void kernel_launch(void* const* d_in, const int* in_sizes, int n_in,
                              void* d_out, int out_size, void* d_ws, size_t ws_size,
                              hipStream_t stream) {
    const void* X      = d_in[0];
    const int*  TE     = (const int*)d_in[1];
    const void* L      = d_in[2];
    const void* SEi    = d_in[3];
    const void* W_se1  = d_in[4];
    const void* b_se1  = d_in[5];
    const void* W_se2  = d_in[6];
    const void* b_se2  = d_in[7];
    const void* W_te1  = d_in[8];
    const void* b_te1  = d_in[9];
    const void* W_te2  = d_in[10];
    const void* b_te2  = d_in[11];
    const void* W_in1  = d_in[12];
    const void* b_in1  = d_in[13];
    const void* W_in2  = d_in[14];
    const void* b_in2  = d_in[15];
    const void* W_gate = d_in[16];
    const void* b_gate = d_in[17];
    const void* W_cand = d_in[18];
    const void* b_cand = d_in[19];
    const void* W_out1 = d_in[20];
    const void* b_out1 = d_in[21];
    const void* W_out2 = d_in[22];
    const void* b_out2 = d_in[23];

    // ---- slim workspace layout (~12.3 MB) ----
    float* ws = (float*)d_ws;
    size_t o = 0;
    int*   flagp   = (int*)(ws + o); o += 16;
    float* ell_val = ws + o; o += (size_t)N_ * ELLW;
    int*   ell_col = (int*)(ws + o); o += (size_t)N_ * ELLW;
    int*   ell_cnt = (int*)(ws + o); o += N_;
    float* se = ws + o; o += (size_t)N_ * D_;
    float* te = ws + o; o += (size_t)B_ * P_ * D_;
    const size_t HSZ = (size_t)B_ * N_ * D_;
    float* xt  = ws + o; o += HSZ;
    float* XT1 = ws + o; o += HSZ;
    float* XT2 = ws + o; o += HSZ;
    float* HC1 = ws + o; o += HSZ;
    float* HC2 = ws + o; o += HSZ;
    float* RC1 = ws + o; o += HSZ;
    float* RC2 = ws + o; o += HSZ;
    float* RH  = ws + o; o += HSZ;
    float* Ub  = ws + o; o += HSZ;
    float* H   = ws + o; o += HSZ;

    hipMemsetAsync(H, 0, HSZ * sizeof(float), stream);
    k_detect<<<1, 256, 0, stream>>>(L, flagp);
    k_build_ell<<<N_, 256, 0, stream>>>(L, flagp, ell_val, ell_col, ell_cnt);
    k_se<<<N_ / 8, 256, 0, stream>>>(SEi, W_se1, b_se1, W_se2, b_se2, flagp, se);
    k_te<<<(B_ * P_) / 8, 256, 0, stream>>>(TE, W_te1, b_te1, W_te2, b_te2, flagp, te);

    for (int t = 0; t < P_; ++t) {
        k_xt<<<B_ * N_ / 8, 256, 0, stream>>>(t, X, W_in1, b_in1, W_in2, b_in2, se, te, flagp, xt);
        k_spmm<<<B_ * 256, 256, 0, stream>>>(xt, nullptr, XT1, ell_val, ell_col, ell_cnt);
        k_spmm<<<B_ * 256, 256, 0, stream>>>(XT1, xt, XT2, ell_val, ell_col, ell_cnt);
        k_spmm<<<B_ * 256, 256, 0, stream>>>(H, nullptr, HC1, ell_val, ell_col, ell_cnt);
        k_spmm<<<B_ * 256, 256, 0, stream>>>(HC1, H, HC2, ell_val, ell_col, ell_cnt);
        k_gate<<<B_ * 256, 256, 0, stream>>>(xt, XT1, XT2, H, HC1, HC2, W_gate, b_gate,
                                             ell_val, ell_col, ell_cnt, flagp, Ub, RH);
        k_spmm<<<B_ * 256, 256, 0, stream>>>(RH, nullptr, RC1, ell_val, ell_col, ell_cnt);
        k_spmm<<<B_ * 256, 256, 0, stream>>>(RC1, RH, RC2, ell_val, ell_col, ell_cnt);
        k_cand<<<B_ * 256, 256, 0, stream>>>(xt, XT1, XT2, RH, RC1, RC2, W_cand, b_cand,
                                             ell_val, ell_col, ell_cnt, flagp, Ub, H);
    }
    k_out<<<B_ * N_ / 256, 256, 0, stream>>>(H, W_out1, b_out1, W_out2, b_out2, flagp, (void*)d_out);
}

// Round 4
// 1288.112 us; speedup vs baseline: 2.0049x; 2.0049x over previous
//
#include <hip/hip_runtime.h>
#include <hip/hip_bf16.h>

#define B_ 4
#define P_ 12
#define Q_ 12
#define N_ 2048
#define D_ 32
#define ELLW 96

typedef __hip_bfloat16 bf16;

// Dual-path input load: flag==0 -> bf16 storage, flag==1 -> fp32 storage.
__device__ __forceinline__ float ld(const void* p, int i, int flag) {
    if (flag) return ((const float*)p)[i];
    unsigned int u = ((const unsigned short*)p)[i];
    return __uint_as_float(u << 16);
}

// ------------------------------------------------------------ dtype detector
__global__ void k_detect(const void* L, int* flagp) {
    __shared__ int c;
    if (threadIdx.x == 0) c = 0;
    __syncthreads();
    const unsigned short* p = (const unsigned short*)L;
    int bad = 0;
    for (int i = threadIdx.x; i < 8192; i += 256) {
        unsigned int u = p[i];
        float v = __uint_as_float(u << 16);
        if (isnan(v) || isinf(v) || (v != 0.f && (fabsf(v) < 1e-8f || fabsf(v) > 1e4f))) bad = 1;
    }
    atomicOr(&c, bad);
    __syncthreads();
    if (threadIdx.x == 0) *flagp = (c != 0) ? 1 : 0;
}

// ---------------------------------------------------------------- ELL build (rows padded to x8 with zeros)
__global__ __launch_bounds__(256) void k_build_ell(const void* L, const int* flagp,
                                                   float* __restrict__ ell_val,
                                                   int* __restrict__ ell_col,
                                                   int* __restrict__ ell_cnt) {
    int flag = *flagp;
    int row = blockIdx.x;
    __shared__ int cnt;
    if (threadIdx.x == 0) cnt = 0;
    __syncthreads();
    for (int c = threadIdx.x; c < N_; c += 256) {
        float v = ld(L, row * N_ + c, flag);
        if (v != 0.0f) {
            int s = atomicAdd(&cnt, 1);
            if (s < ELLW) { ell_col[row * ELLW + s] = c; ell_val[row * ELLW + s] = v; }
        }
    }
    __syncthreads();
    int c = cnt < ELLW ? cnt : ELLW;
    int c8 = (c + 7) & ~7;
    for (int s = c + threadIdx.x; s < c8; s += 256) { ell_col[row * ELLW + s] = 0; ell_val[row * ELLW + s] = 0.f; }
    if (threadIdx.x == 0) ell_cnt[row] = c8;
}

// ---------------------------------------------------------------- se = relu(SE@W1+b1)@W2+b2
__global__ __launch_bounds__(256) void k_se(const void* SE, const void* W1, const void* B1,
                                            const void* W2, const void* B2, const int* flagp,
                                            float* __restrict__ se) {
    __shared__ float w1[1024], w2[1024], c1[32], c2[32];
    __shared__ float srow[8][33], hid[8][33];
    int flag = *flagp;
    int tid = threadIdx.x;
    for (int i = tid; i < 1024; i += 256) { w1[i] = ld(W1, i, flag); w2[i] = ld(W2, i, flag); }
    if (tid < 32) { c1[tid] = ld(B1, tid, flag); c2[tid] = ld(B2, tid, flag); }
    int r = tid >> 5, d = tid & 31;
    int row = blockIdx.x * 8 + r;
    srow[r][d] = ld(SE, row * 32 + d, flag);
    __syncthreads();
    float a = c1[d];
    #pragma unroll
    for (int i = 0; i < 32; ++i) a += srow[r][i] * w1[i * 32 + d];
    hid[r][d] = fmaxf(a, 0.f);
    __syncthreads();
    float o = c2[d];
    #pragma unroll
    for (int i = 0; i < 32; ++i) o += hid[r][i] * w2[i * 32 + d];
    se[row * 32 + d] = o;
}

// ---------------------------------------------------------------- te
__global__ __launch_bounds__(256) void k_te(const int* __restrict__ TE, const void* W1, const void* B1,
                                            const void* W2, const void* B2, const int* flagp,
                                            float* __restrict__ te) {
    __shared__ float w2[1024], c1[32], c2[32];
    __shared__ float hid[8][33];
    int flag = *flagp;
    int tid = threadIdx.x;
    for (int i = tid; i < 1024; i += 256) w2[i] = ld(W2, i, flag);
    if (tid < 32) { c1[tid] = ld(B1, tid, flag); c2[tid] = ld(B2, tid, flag); }
    __syncthreads();
    int r = tid >> 5, d = tid & 31;
    int row = blockIdx.x * 8 + r;   // row = b*P + t
    int b = row / P_, t = row % P_;
    int day = TE[(b * (P_ + Q_) + t) * 2 + 0];
    int tod = TE[(b * (P_ + Q_) + t) * 2 + 1];
    float a = ld(W1, day * 32 + d, flag) + ld(W1, (7 + tod) * 32 + d, flag) + c1[d];
    hid[r][d] = fmaxf(a, 0.f);
    __syncthreads();
    float o = c2[d];
    #pragma unroll
    for (int i = 0; i < 32; ++i) o += hid[r][i] * w2[i * 32 + d];
    te[row * 32 + d] = o;
}

// ---------------------------------------------------------------- xt for all (t,b): T0 + fold order-0 into GX/CX (init w/ bias)
__global__ __launch_bounds__(256) void k_xt_fold(const void* X, const void* W_in1, const void* b_in1,
        const void* W_in2, const void* b_in2, const void* W_gate, const void* b_gate,
        const void* W_cand, const void* b_cand,
        const float* __restrict__ se, const float* __restrict__ te, const int* flagp,
        float* __restrict__ T0, float* __restrict__ GX, float* __restrict__ CX) {
    __shared__ float w2[1024], wg0[2048], wc0[1024];
    __shared__ float w1s[32], c1s[32], c2s[32];
    __shared__ float hid[32][33];
    __shared__ float st[32][36];   // [feat][row]
    int flag = *flagp;
    int tid = threadIdx.x;
    for (int i = tid; i < 1024; i += 256) w2[i] = ld(W_in2, i, flag);
    for (int i = tid; i < 2048; i += 256) { int j = i >> 6, c = i & 63; wg0[i] = ld(W_gate, j * 64 + c, flag); }
    for (int i = tid; i < 1024; i += 256) { int j = i >> 5, c = i & 31; wc0[i] = ld(W_cand, j * 32 + c, flag); }
    if (tid < 32) { w1s[tid] = ld(W_in1, tid, flag); c1s[tid] = ld(b_in1, tid, flag); c2s[tid] = ld(b_in2, tid, flag); }
    __syncthreads();
    int sr = tid >> 5, d = tid & 31;
    int g0 = blockIdx.x * 32;
    #pragma unroll
    for (int rr = 0; rr < 4; ++rr) {
        int lrow = sr * 4 + rr;
        int g = g0 + lrow;
        int t = g / (B_ * N_); int rem = g - t * B_ * N_; int b = rem >> 11; int n = rem & (N_ - 1);
        float xv = ld(X, (b * P_ + t) * N_ + n, flag);
        hid[lrow][d] = fmaxf(xv * w1s[d] + c1s[d], 0.f);
    }
    __syncthreads();
    #pragma unroll
    for (int rr = 0; rr < 4; ++rr) {
        int lrow = sr * 4 + rr;
        int g = g0 + lrow;
        int t = g / (B_ * N_); int rem = g - t * B_ * N_; int b = rem >> 11; int n = rem & (N_ - 1);
        float o = c2s[d] + se[n * 32 + d] + te[(b * P_ + t) * 32 + d];
        #pragma unroll
        for (int i = 0; i < 32; ++i) o += hid[lrow][i] * w2[i * 32 + d];
        T0[(size_t)g * 32 + d] = o;
        st[d][lrow] = o;
    }
    __syncthreads();
    int d0 = tid & 31, rg = tid >> 5;   // rows rg*4..+3
    float a0[4], a1[4], ac[4];
    float bg0 = ld(b_gate, d0, flag), bg1 = ld(b_gate, 32 + d0, flag), bcv = ld(b_cand, d0, flag);
    #pragma unroll
    for (int i = 0; i < 4; ++i) { a0[i] = bg0; a1[i] = bg1; ac[i] = bcv; }
    #pragma unroll 4
    for (int j = 0; j < 32; ++j) {
        float4 v = *(const float4*)&st[j][rg * 4];
        float u0 = wg0[j * 64 + d0], u1 = wg0[j * 64 + 32 + d0], uc = wc0[j * 32 + d0];
        a0[0] += v.x * u0; a0[1] += v.y * u0; a0[2] += v.z * u0; a0[3] += v.w * u0;
        a1[0] += v.x * u1; a1[1] += v.y * u1; a1[2] += v.z * u1; a1[3] += v.w * u1;
        ac[0] += v.x * uc; ac[1] += v.y * uc; ac[2] += v.z * uc; ac[3] += v.w * uc;
    }
    #pragma unroll
    for (int i = 0; i < 4; ++i) {
        int g = g0 + rg * 4 + i;
        GX[(size_t)g * 64 + d0] = a0[i];
        GX[(size_t)g * 64 + 32 + d0] = a1[i];
        CX[(size_t)g * 32 + d0] = ac[i];
    }
}

// ---------------------------------------------------------------- Chebyshev hop over 48 slices + fused fold order-k (RMW GX/CX)
__global__ __launch_bounds__(256) void k_hop_fold(int k, const float* __restrict__ in, const float* __restrict__ prevb,
        float* __restrict__ outT, const void* W_gate, const void* W_cand,
        const float* __restrict__ ell_val, const int* __restrict__ ell_col, const int* __restrict__ ell_cnt,
        const int* flagp, float* __restrict__ GX, float* __restrict__ CX) {
    __shared__ float wgk[2048], wck[1024];
    __shared__ float st[32][36];
    int flag = *flagp;
    int tid = threadIdx.x;
    for (int i = tid; i < 2048; i += 256) { int j = i >> 6, c = i & 63; wgk[i] = ld(W_gate, (k * 64 + j) * 64 + c, flag); }
    for (int i = tid; i < 1024; i += 256) { int j = i >> 5, c = i & 31; wck[i] = ld(W_cand, (k * 64 + j) * 32 + c, flag); }
    int sr = tid >> 5, d = tid & 31;
    int slice = blockIdx.x >> 6;          // 64 blocks per slice
    int rb = blockIdx.x & 63;
    const float* inS = in + (size_t)slice * N_ * 32;
    __syncthreads();
    #pragma unroll
    for (int rr = 0; rr < 4; ++rr) {
        int lrow = sr * 4 + rr;
        int row = rb * 32 + lrow;
        int cnt = ell_cnt[row];
        const int* cols = ell_col + row * ELLW;
        const float* vals = ell_val + row * ELLW;
        float acc = 0.f;
        for (int i = 0; i < cnt; i += 8) {
            #pragma unroll
            for (int q = 0; q < 8; ++q) acc += vals[i + q] * inS[cols[i + q] * 32 + d];
        }
        size_t idx = (size_t)slice * N_ * 32 + (size_t)row * 32 + d;
        float tv = prevb ? (2.f * acc - prevb[idx]) : acc;
        if (outT) outT[idx] = tv;
        st[d][lrow] = tv;
    }
    __syncthreads();
    int d0 = tid & 31, rg = tid >> 5;
    int grow0 = slice * N_ + rb * 32 + rg * 4;
    float a0[4], a1[4], ac[4];
    #pragma unroll
    for (int i = 0; i < 4; ++i) {
        int g = grow0 + i;
        a0[i] = GX[(size_t)g * 64 + d0];
        a1[i] = GX[(size_t)g * 64 + 32 + d0];
        ac[i] = CX[(size_t)g * 32 + d0];
    }
    #pragma unroll 4
    for (int j = 0; j < 32; ++j) {
        float4 v = *(const float4*)&st[j][rg * 4];
        float u0 = wgk[j * 64 + d0], u1 = wgk[j * 64 + 32 + d0], uc = wck[j * 32 + d0];
        a0[0] += v.x * u0; a0[1] += v.y * u0; a0[2] += v.z * u0; a0[3] += v.w * u0;
        a1[0] += v.x * u1; a1[1] += v.y * u1; a1[2] += v.z * u1; a1[3] += v.w * u1;
        ac[0] += v.x * uc; ac[1] += v.y * uc; ac[2] += v.z * uc; ac[3] += v.w * uc;
    }
    #pragma unroll
    for (int i = 0; i < 4; ++i) {
        int g = grow0 + i;
        GX[(size_t)g * 64 + d0] = a0[i];
        GX[(size_t)g * 64 + 32 + d0] = a1[i];
        CX[(size_t)g * 32 + d0] = ac[i];
    }
}

// ---------------------------------------------------------------- in-loop hop over B slices, 8 rows/block, 4 slices/thread
__global__ __launch_bounds__(256) void k_spmm4(const float* __restrict__ in, const float* __restrict__ prevb,
                                               float* __restrict__ out,
                                               const float* __restrict__ ell_val, const int* __restrict__ ell_col,
                                               const int* __restrict__ ell_cnt) {
    int r = threadIdx.x >> 5, d = threadIdx.x & 31;
    int row = blockIdx.x * 8 + r;
    int cnt = ell_cnt[row];
    const int* cols = ell_col + row * ELLW;
    const float* vals = ell_val + row * ELLW;
    const size_t NS = (size_t)N_ * 32;
    float a0 = 0.f, a1 = 0.f, a2 = 0.f, a3 = 0.f;
    for (int i = 0; i < cnt; i += 8) {
        #pragma unroll
        for (int q = 0; q < 8; ++q) {
            int c = cols[i + q]; float v = vals[i + q];
            int off = c * 32 + d;
            a0 += v * in[off];
            a1 += v * in[NS + off];
            a2 += v * in[2 * NS + off];
            a3 += v * in[3 * NS + off];
        }
    }
    size_t idx = (size_t)row * 32 + d;
    if (prevb) {
        out[idx]          = 2.f * a0 - prevb[idx];
        out[NS + idx]     = 2.f * a1 - prevb[NS + idx];
        out[2 * NS + idx] = 2.f * a2 - prevb[2 * NS + idx];
        out[3 * NS + idx] = 2.f * a3 - prevb[3 * NS + idx];
    } else {
        out[idx] = a0; out[NS + idx] = a1; out[2 * NS + idx] = a2; out[3 * NS + idx] = a3;
    }
}

// ---------------------------------------------------------------- gate: h-half GEMM (128x64) + fused hop3 + sigmoid
__global__ __launch_bounds__(256) void k_gate(const float* __restrict__ H, const float* __restrict__ HC1,
                                              const float* __restrict__ HC2, const float* __restrict__ GXt,
                                              const void* W_gate,
                                              const float* __restrict__ ell_val, const int* __restrict__ ell_col,
                                              const int* __restrict__ ell_cnt, const int* flagp,
                                              float* __restrict__ U, float* __restrict__ RH) {
    __shared__ float wg[128 * 64];   // 32 KB, h-half
    __shared__ float st[128][36];    // [feat][row], 18.4 KB
    int flag = *flagp;
    int tid = threadIdx.x;
    for (int i = tid; i < 8192; i += 256) {
        int kk = i >> 6, c = i & 63;
        wg[i] = ld(W_gate, ((kk >> 5) * 64 + 32 + (kk & 31)) * 64 + c, flag);
    }
    int sr = tid >> 5, d = tid & 31;
    int b = blockIdx.x >> 6;                 // 64 blocks per b
    const float* H2s = HC2 + (size_t)b * N_ * 32;
    #pragma unroll
    for (int rr = 0; rr < 4; ++rr) {
        int lrow = sr * 4 + rr;
        int grow = blockIdx.x * 32 + lrow;
        int n = grow & (N_ - 1);
        size_t idx = (size_t)grow * 32 + d;
        float hv = H[idx], h1 = HC1[idx], h2 = HC2[idx];
        int cnt = ell_cnt[n];
        const int* cols = ell_col + n * ELLW;
        const float* vals = ell_val + n * ELLW;
        float acc = 0.f;
        for (int i = 0; i < cnt; i += 8) {
            #pragma unroll
            for (int q = 0; q < 8; ++q) acc += vals[i + q] * H2s[cols[i + q] * 32 + d];
        }
        st[d][lrow] = hv;
        st[32 + d][lrow] = h1;
        st[64 + d][lrow] = h2;
        st[96 + d][lrow] = 2.f * acc - h1;
    }
    __syncthreads();
    int d0 = tid & 31, rg = tid >> 5;
    int grow0 = blockIdx.x * 32 + rg * 4;
    float a0[4], a1[4];
    #pragma unroll
    for (int i = 0; i < 4; ++i) {
        a0[i] = GXt[(size_t)(grow0 + i) * 64 + d0];
        a1[i] = GXt[(size_t)(grow0 + i) * 64 + 32 + d0];
    }
    #pragma unroll 4
    for (int kk = 0; kk < 128; ++kk) {
        float4 v = *(const float4*)&st[kk][rg * 4];
        float u0 = wg[kk * 64 + d0], u1 = wg[kk * 64 + 32 + d0];
        a0[0] += v.x * u0; a0[1] += v.y * u0; a0[2] += v.z * u0; a0[3] += v.w * u0;
        a1[0] += v.x * u1; a1[1] += v.y * u1; a1[2] += v.z * u1; a1[3] += v.w * u1;
    }
    #pragma unroll
    for (int i = 0; i < 4; ++i) {
        float rv = 1.f / (1.f + expf(-a0[i]));
        float uv = 1.f / (1.f + expf(-a1[i]));
        float hvv = st[d0][rg * 4 + i];
        size_t idx = (size_t)(grow0 + i) * 32 + d0;
        U[idx] = uv;
        RH[idx] = rv * hvv;
    }
}

// ---------------------------------------------------------------- cand: h-half GEMM (128x32) + fused hop3 + tanh + GRU update
__global__ __launch_bounds__(256) void k_cand(const float* __restrict__ RHv, const float* __restrict__ RC1,
                                              const float* __restrict__ RC2, const float* __restrict__ CXt,
                                              const void* W_cand,
                                              const float* __restrict__ ell_val, const int* __restrict__ ell_col,
                                              const int* __restrict__ ell_cnt, const int* flagp,
                                              const float* __restrict__ U, float* __restrict__ H) {
    __shared__ float wc[128 * 32];   // 16 KB
    __shared__ float st[128][36];
    int flag = *flagp;
    int tid = threadIdx.x;
    for (int i = tid; i < 4096; i += 256) {
        int kk = i >> 5, c = i & 31;
        wc[i] = ld(W_cand, ((kk >> 5) * 64 + 32 + (kk & 31)) * 32 + c, flag);
    }
    int sr = tid >> 5, d = tid & 31;
    int b = blockIdx.x >> 6;
    const float* R2s = RC2 + (size_t)b * N_ * 32;
    #pragma unroll
    for (int rr = 0; rr < 4; ++rr) {
        int lrow = sr * 4 + rr;
        int grow = blockIdx.x * 32 + lrow;
        int n = grow & (N_ - 1);
        size_t idx = (size_t)grow * 32 + d;
        float rh = RHv[idx], r1 = RC1[idx], r2 = RC2[idx];
        int cnt = ell_cnt[n];
        const int* cols = ell_col + n * ELLW;
        const float* vals = ell_val + n * ELLW;
        float acc = 0.f;
        for (int i = 0; i < cnt; i += 8) {
            #pragma unroll
            for (int q = 0; q < 8; ++q) acc += vals[i + q] * R2s[cols[i + q] * 32 + d];
        }
        st[d][lrow] = rh;
        st[32 + d][lrow] = r1;
        st[64 + d][lrow] = r2;
        st[96 + d][lrow] = 2.f * acc - r1;
    }
    __syncthreads();
    int d0 = tid & 31, rg = tid >> 5;
    int grow0 = blockIdx.x * 32 + rg * 4;
    float ac[4];
    #pragma unroll
    for (int i = 0; i < 4; ++i) ac[i] = CXt[(size_t)(grow0 + i) * 32 + d0];
    #pragma unroll 4
    for (int kk = 0; kk < 128; ++kk) {
        float4 v = *(const float4*)&st[kk][rg * 4];
        float uc = wc[kk * 32 + d0];
        ac[0] += v.x * uc; ac[1] += v.y * uc; ac[2] += v.z * uc; ac[3] += v.w * uc;
    }
    #pragma unroll
    for (int i = 0; i < 4; ++i) {
        float c = tanhf(ac[i]);
        size_t idx = (size_t)(grow0 + i) * 32 + d0;
        float uv = U[idx];
        float hv = H[idx];
        H[idx] = uv * hv + (1.f - uv) * c;
    }
}

// ---------------------------------------------------------------- output head
__global__ __launch_bounds__(256) void k_out(const float* __restrict__ H, const void* W1, const void* B1,
                                             const void* W2, const void* B2, const int* flagp,
                                             void* __restrict__ out) {
    __shared__ float w1[1024], w2[384], c1[32], c2[12];
    int flag = *flagp;
    int tid = threadIdx.x;
    for (int i = tid; i < 1024; i += 256) w1[i] = ld(W1, i, flag);
    for (int i = tid; i < 384; i += 256) w2[i] = ld(W2, i, flag);
    if (tid < 32) c1[tid] = ld(B1, tid, flag);
    if (tid < 12) c2[tid] = ld(B2, tid, flag);
    __syncthreads();
    int gid = blockIdx.x * 256 + tid;
    int b = gid / N_, n = gid % N_;
    float hrow[32];
    #pragma unroll
    for (int i = 0; i < 32; ++i) hrow[i] = H[(size_t)(b * N_ + n) * 32 + i];
    float hid[32];
    #pragma unroll
    for (int j = 0; j < 32; ++j) {
        float a = c1[j];
        #pragma unroll
        for (int i = 0; i < 32; ++i) a += hrow[i] * w1[i * 32 + j];
        hid[j] = fmaxf(a, 0.f);
    }
    for (int q = 0; q < 12; ++q) {
        float a = c2[q];
        #pragma unroll
        for (int j = 0; j < 32; ++j) a += hid[j] * w2[j * 12 + q];
        size_t idx = ((size_t)b * Q_ + q) * N_ + n;
        if (flag) ((float*)out)[idx] = a;
        else ((bf16*)out)[idx] = __float2bfloat16(a);
    }
}

extern "C" void kernel_launch(void* const* d_in, const int* in_sizes, int n_in,
                              void* d_out, int out_size, void* d_ws, size_t ws_size,
                              hipStream_t stream) {
    const void* X      = d_in[0];
    const int*  TE     = (const int*)d_in[1];
    const void* L      = d_in[2];
    const void* SEi    = d_in[3];
    const void* W_se1  = d_in[4];
    const void* b_se1  = d_in[5];
    const void* W_se2  = d_in[6];
    const void* b_se2  = d_in[7];
    const void* W_te1  = d_in[8];
    const void* b_te1  = d_in[9];
    const void* W_te2  = d_in[10];
    const void* b_te2  = d_in[11];
    const void* W_in1  = d_in[12];
    const void* b_in1  = d_in[13];
    const void* W_in2  = d_in[14];
    const void* b_in2  = d_in[15];
    const void* W_gate = d_in[16];
    const void* b_gate = d_in[17];
    const void* W_cand = d_in[18];
    const void* b_cand = d_in[19];
    const void* W_out1 = d_in[20];
    const void* b_out1 = d_in[21];
    const void* W_out2 = d_in[22];
    const void* b_out2 = d_in[23];

    // ---- workspace layout (~74 MB) ----
    float* ws = (float*)d_ws;
    size_t o = 0;
    int*   flagp   = (int*)(ws + o); o += 16;
    float* ell_val = ws + o; o += (size_t)N_ * ELLW;
    int*   ell_col = (int*)(ws + o); o += (size_t)N_ * ELLW;
    int*   ell_cnt = (int*)(ws + o); o += N_;
    float* se = ws + o; o += (size_t)N_ * 32;
    float* te = ws + o; o += (size_t)B_ * P_ * 32;
    const size_t TSZ = (size_t)P_ * B_ * N_ * 32;
    float* Ta = ws + o; o += TSZ;                       // T0, later T2 (in place)
    float* Tb = ws + o; o += TSZ;                       // T1
    float* GX = ws + o; o += (size_t)P_ * B_ * N_ * 64;
    float* CX = ws + o; o += TSZ;
    const size_t HSZ = (size_t)B_ * N_ * 32;
    float* H   = ws + o; o += HSZ;
    float* HC1 = ws + o; o += HSZ;
    float* HC2 = ws + o; o += HSZ;
    float* RH  = ws + o; o += HSZ;
    float* RC1 = ws + o; o += HSZ;
    float* RC2 = ws + o; o += HSZ;
    float* Ub  = ws + o; o += HSZ;

    hipMemsetAsync(H, 0, HSZ * sizeof(float), stream);
    k_detect<<<1, 256, 0, stream>>>(L, flagp);
    k_build_ell<<<N_, 256, 0, stream>>>(L, flagp, ell_val, ell_col, ell_cnt);
    k_se<<<N_ / 8, 256, 0, stream>>>(SEi, W_se1, b_se1, W_se2, b_se2, flagp, se);
    k_te<<<(B_ * P_) / 8, 256, 0, stream>>>(TE, W_te1, b_te1, W_te2, b_te2, flagp, te);

    // x-side Chebyshev + fold (once, batched over all t,b)
    const int GBIG = P_ * B_ * N_ / 32;     // 3072
    k_xt_fold<<<GBIG, 256, 0, stream>>>(X, W_in1, b_in1, W_in2, b_in2, W_gate, b_gate, W_cand, b_cand,
                                        se, te, flagp, Ta, GX, CX);
    // T1 = L@T0 -> Tb; fold k=1
    k_hop_fold<<<GBIG, 256, 0, stream>>>(1, Ta, nullptr, Tb, W_gate, W_cand,
                                         ell_val, ell_col, ell_cnt, flagp, GX, CX);
    // T2 = 2L@T1 - T0 -> Ta (in place over T0, elementwise-safe); fold k=2
    k_hop_fold<<<GBIG, 256, 0, stream>>>(2, Tb, Ta, Ta, W_gate, W_cand,
                                         ell_val, ell_col, ell_cnt, flagp, GX, CX);
    // T3 = 2L@T2 - T1 (not stored); fold k=3
    k_hop_fold<<<GBIG, 256, 0, stream>>>(3, Ta, Tb, nullptr, W_gate, W_cand,
                                         ell_val, ell_col, ell_cnt, flagp, GX, CX);

    for (int t = 0; t < P_; ++t) {
        const float* GXt = GX + (size_t)t * B_ * N_ * 64;
        const float* CXt = CX + (size_t)t * B_ * N_ * 32;
        k_spmm4<<<N_ / 8, 256, 0, stream>>>(H, nullptr, HC1, ell_val, ell_col, ell_cnt);
        k_spmm4<<<N_ / 8, 256, 0, stream>>>(HC1, H, HC2, ell_val, ell_col, ell_cnt);
        k_gate<<<B_ * N_ / 32, 256, 0, stream>>>(H, HC1, HC2, GXt, W_gate,
                                                 ell_val, ell_col, ell_cnt, flagp, Ub, RH);
        k_spmm4<<<N_ / 8, 256, 0, stream>>>(RH, nullptr, RC1, ell_val, ell_col, ell_cnt);
        k_spmm4<<<N_ / 8, 256, 0, stream>>>(RC1, RH, RC2, ell_val, ell_col, ell_cnt);
        k_cand<<<B_ * N_ / 32, 256, 0, stream>>>(RH, RC1, RC2, CXt, W_cand,
                                                 ell_val, ell_col, ell_cnt, flagp, Ub, H);
    }
    k_out<<<B_ * N_ / 256, 256, 0, stream>>>(H, W_out1, b_out1, W_out2, b_out2, flagp, (void*)d_out);
}